// Round 1
// baseline (286.854 us; speedup 1.0000x reference)
//
#include <hip/hip_runtime.h>
#include <stdint.h>

// Problem dims
#define L_SEQ 8192
#define HDIM  1024
#define PDIM  512
#define RDIM  256
#define NCHUNK 64
#define CHUNK  128

typedef __attribute__((ext_vector_type(8))) short bf16x8;
typedef __attribute__((ext_vector_type(4))) float f32x4;
typedef __attribute__((ext_vector_type(4))) int   i32x4;

__device__ inline unsigned short f2bf(float x) {
  unsigned u = __builtin_bit_cast(unsigned, x);
  unsigned r = (u + 0x7fffu + ((u >> 16) & 1u)) >> 16;
  return (unsigned short)r;
}

// ---------------------------------------------------------------------------
// Transpose + cast: src (R x Hd) f32  ->  dst (Hd x R) bf16
// ---------------------------------------------------------------------------
__global__ __launch_bounds__(256) void transpose_cast(const float* __restrict__ src,
                                                      unsigned short* __restrict__ dst,
                                                      int R, int Hd) {
  __shared__ float tile[32][33];
  int bx = blockIdx.x * 32;  // over Hd (src cols)
  int by = blockIdx.y * 32;  // over R (src rows)
  int tx = threadIdx.x, ty = threadIdx.y;  // (32, 8)
#pragma unroll
  for (int dy = 0; dy < 32; dy += 8)
    tile[ty + dy][tx] = src[(size_t)(by + ty + dy) * Hd + bx + tx];
  __syncthreads();
#pragma unroll
  for (int dy = 0; dy < 32; dy += 8)
    dst[(size_t)(bx + ty + dy) * R + by + tx] = f2bf(tile[tx][ty + dy]);
}

// ---------------------------------------------------------------------------
// Flat cast f32 -> bf16 (with scale), n4 = count/4
// ---------------------------------------------------------------------------
__global__ __launch_bounds__(256) void cast_flat(const float* __restrict__ src,
                                                 unsigned short* __restrict__ dst,
                                                 int n4, float scale) {
  int g = blockIdx.x * 256 + threadIdx.x;
  if (g >= n4) return;
  float4 v = *(const float4*)(src + (size_t)g * 4);
  ushort4 o;
  o.x = f2bf(v.x * scale); o.y = f2bf(v.y * scale);
  o.z = f2bf(v.z * scale); o.w = f2bf(v.w * scale);
  *(ushort4*)(dst + (size_t)g * 4) = o;
}

// ---------------------------------------------------------------------------
// Strided cast f32 -> bf16 (with scale)
// ---------------------------------------------------------------------------
__global__ __launch_bounds__(256) void cast_strided(const float* __restrict__ src, int ldsrc,
                                                    unsigned short* __restrict__ dst, int lddst,
                                                    int rows, int cols, float scale) {
  int g = blockIdx.x * 256 + threadIdx.x;
  int c4 = cols >> 2;
  int total = rows * c4;
  if (g >= total) return;
  int row = g / c4;
  int c = (g - row * c4) * 4;
  float4 v = *(const float4*)(src + (size_t)row * ldsrc + c);
  ushort4 o;
  o.x = f2bf(v.x * scale); o.y = f2bf(v.y * scale);
  o.z = f2bf(v.z * scale); o.w = f2bf(v.w * scale);
  *(ushort4*)(dst + (size_t)row * lddst + c) = o;
}

// ---------------------------------------------------------------------------
// bf16 MFMA GEMM:  C(MxN) = A(MxK) @ B(NxK)^T  [+ Add]
// 128x128 tile, 4 waves (2x2), each wave 64x64 via 4x4 mfma_16x16x32 frags.
// M,N multiples of 128; K multiple of 32. Reg-staged LDS, single-buffered.
// ---------------------------------------------------------------------------
template <int HAS_ADD, int OUT_F32, int OUT_BF16>
__global__ __launch_bounds__(256) void gemm_bt(const unsigned short* __restrict__ A, int lda,
                                               const unsigned short* __restrict__ B, int ldb,
                                               float* __restrict__ C, int ldc,
                                               unsigned short* __restrict__ Cb, int ldcb,
                                               const float* __restrict__ Add, int ldadd,
                                               int K) {
  __shared__ __align__(16) unsigned short sA[128 * 32];
  __shared__ __align__(16) unsigned short sB[128 * 32];
  const int m0 = blockIdx.x * 128, n0 = blockIdx.y * 128;
  const int tid = threadIdx.x;
  const int lane = tid & 63, wave = tid >> 6;
  const int wm = wave >> 1, wn = wave & 1;
  const int frow = lane & 15, fg = lane >> 4;

  f32x4 acc[4][4] = {};

  for (int kt = 0; kt < K; kt += 32) {
    i32x4 ra[2], rb[2];
#pragma unroll
    for (int it = 0; it < 2; ++it) {
      int flat = it * 256 + tid;
      int r = flat >> 2, c8 = (flat & 3) * 8;
      ra[it] = *(const i32x4*)(A + (size_t)(m0 + r) * lda + kt + c8);
      rb[it] = *(const i32x4*)(B + (size_t)(n0 + r) * ldb + kt + c8);
    }
    __syncthreads();  // previous iteration's LDS reads complete
#pragma unroll
    for (int it = 0; it < 2; ++it) {
      int flat = it * 256 + tid;
      int r = flat >> 2, c8 = (flat & 3) * 8;
      *(i32x4*)(sA + r * 32 + c8) = ra[it];
      *(i32x4*)(sB + r * 32 + c8) = rb[it];
    }
    __syncthreads();
    bf16x8 fa[4], fb[4];
#pragma unroll
    for (int f = 0; f < 4; ++f) {
      fa[f] = *(const bf16x8*)(sA + (wm * 64 + f * 16 + frow) * 32 + fg * 8);
      fb[f] = *(const bf16x8*)(sB + (wn * 64 + f * 16 + frow) * 32 + fg * 8);
    }
#pragma unroll
    for (int i = 0; i < 4; ++i)
#pragma unroll
      for (int j = 0; j < 4; ++j)
        acc[i][j] = __builtin_amdgcn_mfma_f32_16x16x32_bf16(fa[i], fb[j], acc[i][j], 0, 0, 0);
  }

  // Epilogue: verified C/D layout col=lane&15, row=(lane>>4)*4+reg
  const int crow4 = (lane >> 4) * 4, ccol = lane & 15;
#pragma unroll
  for (int i = 0; i < 4; ++i)
#pragma unroll
    for (int j = 0; j < 4; ++j)
#pragma unroll
      for (int q = 0; q < 4; ++q) {
        int r = m0 + wm * 64 + i * 16 + crow4 + q;
        int c = n0 + wn * 64 + j * 16 + ccol;
        float v = acc[i][j][q];
        if (HAS_ADD) v += Add[(size_t)r * ldadd + c];
        if (OUT_F32) C[(size_t)r * ldc + c] = v;
        if (OUT_BF16) Cb[(size_t)r * ldcb + c] = f2bf(v);
      }
}

// ---------------------------------------------------------------------------
// Scan phase 1: per (channel, chunk) local scan from 0, emit carry only.
// Bu layout: (L, 1024) f32, col p = re, col 512+p = im.
// ---------------------------------------------------------------------------
__global__ __launch_bounds__(256) void scan_carry(const float* __restrict__ Bu,
                                                  const float* __restrict__ lre,
                                                  const float* __restrict__ lim,
                                                  float* __restrict__ carry) {
  int g = blockIdx.x * 256 + threadIdx.x;  // 0..32767
  int p = g & 511, c = g >> 9;
  float ar = lre[p], ai = lim[p];
  float sr = 0.f, si = 0.f;
  const float* base = Bu + (size_t)c * CHUNK * 1024 + p;
#pragma unroll 4
  for (int i = 0; i < CHUNK; ++i) {
    float br = base[(size_t)i * 1024];
    float bi = base[(size_t)i * 1024 + 512];
    float nr = ar * sr - ai * si + br;
    float ni = ar * si + ai * sr + bi;
    sr = nr; si = ni;
  }
  carry[c * 512 + p] = sr;
  carry[NCHUNK * 512 + c * 512 + p] = si;
}

// ---------------------------------------------------------------------------
// Scan phase 2: per channel, sequentially combine chunk carries.
// prefix[c] = state at END of chunk c.
// ---------------------------------------------------------------------------
__global__ __launch_bounds__(512) void scan_prefix(const float* __restrict__ carry,
                                                   const float* __restrict__ lre,
                                                   const float* __restrict__ lim,
                                                   float* __restrict__ prefix) {
  int p = threadIdx.x;  // 512
  float ar = lre[p], ai = lim[p];
  // lam^CHUNK via 7 squarings (CHUNK = 128 = 2^7)
  float cr = ar, ci = ai;
#pragma unroll
  for (int s = 0; s < 7; ++s) {
    float t = cr * cr - ci * ci;
    ci = 2.f * cr * ci;
    cr = t;
  }
  float sr = 0.f, si = 0.f;
  for (int c = 0; c < NCHUNK; ++c) {
    float br = carry[c * 512 + p], bi = carry[NCHUNK * 512 + c * 512 + p];
    float nr = cr * sr - ci * si + br;
    float ni = cr * si + ci * sr + bi;
    sr = nr; si = ni;
    prefix[c * 512 + p] = sr;
    prefix[NCHUNK * 512 + c * 512 + p] = si;
  }
}

// ---------------------------------------------------------------------------
// Scan phase 3: re-scan with correct init, write bf16 x into A2 cols [1024,2048)
// A2 row layout: [0,1024) = u, [1024,1536) = x_re, [1536,2048) = x_im
// ---------------------------------------------------------------------------
__global__ __launch_bounds__(256) void scan_apply(const float* __restrict__ Bu,
                                                  const float* __restrict__ lre,
                                                  const float* __restrict__ lim,
                                                  const float* __restrict__ prefix,
                                                  unsigned short* __restrict__ A2) {
  int g = blockIdx.x * 256 + threadIdx.x;
  int p = g & 511, c = g >> 9;
  float ar = lre[p], ai = lim[p];
  float sr = 0.f, si = 0.f;
  if (c > 0) {
    sr = prefix[(c - 1) * 512 + p];
    si = prefix[NCHUNK * 512 + (c - 1) * 512 + p];
  }
  const float* base = Bu + (size_t)c * CHUNK * 1024 + p;
  unsigned short* ob = A2 + (size_t)c * CHUNK * 2048 + 1024 + p;
#pragma unroll 4
  for (int i = 0; i < CHUNK; ++i) {
    float br = base[(size_t)i * 1024];
    float bi = base[(size_t)i * 1024 + 512];
    float nr = ar * sr - ai * si + br;
    float ni = ar * si + ai * sr + bi;
    sr = nr; si = ni;
    ob[(size_t)i * 2048] = f2bf(sr);
    ob[(size_t)i * 2048 + 512] = f2bf(si);
  }
}

// ---------------------------------------------------------------------------
extern "C" void kernel_launch(void* const* d_in, const int* in_sizes, int n_in,
                              void* d_out, int out_size, void* d_ws, size_t ws_size,
                              hipStream_t stream) {
  const float* u   = (const float*)d_in[0];   // (L, H)
  const float* F   = (const float*)d_in[1];   // (R, H)
  const float* Hp  = (const float*)d_in[2];   // (R, H)
  const float* dP  = (const float*)d_in[3];   // (R, R)
  const float* dR  = (const float*)d_in[4];   // (R, R)
  const float* E   = (const float*)d_in[5];   // (P, R)
  const float* G   = (const float*)d_in[6];   // (H, R)
  const float* lre = (const float*)d_in[7];   // (P,)
  const float* lim = (const float*)d_in[8];   // (P,)
  const float* Bre = (const float*)d_in[9];   // (P, H)
  const float* Bim = (const float*)d_in[10];  // (P, H)
  const float* Cre = (const float*)d_in[11];  // (H, P)
  const float* Cim = (const float*)d_in[12];  // (H, P)
  const float* Dm  = (const float*)d_in[13];  // (H, H)
  float* y = (float*)d_out;

  uint8_t* ws = (uint8_t*)d_ws;
  size_t off = 0;
  auto alloc = [&](size_t bytes) {
    void* p = ws + off;
    off += (bytes + 255) & ~(size_t)255;
    return p;
  };
  unsigned short* A2  = (unsigned short*)alloc((size_t)L_SEQ * 2048 * 2);  // [u | x_re | x_im] bf16
  unsigned short* W1  = (unsigned short*)alloc((size_t)1024 * 1024 * 2);   // [B're ; B_im] bf16
  unsigned short* Wy  = (unsigned short*)alloc((size_t)1024 * 2048 * 2);   // [D' | 2C_re | -2C_im] bf16
  float*          Bu  = (float*)alloc((size_t)L_SEQ * 1024 * 4);           // driving terms f32
  unsigned short* Ft  = (unsigned short*)alloc((size_t)1024 * 256 * 2);
  unsigned short* Ht  = (unsigned short*)alloc((size_t)1024 * 256 * 2);
  unsigned short* FpT = (unsigned short*)alloc((size_t)1024 * 256 * 2);
  unsigned short* HrT = (unsigned short*)alloc((size_t)1024 * 256 * 2);
  unsigned short* dPb = (unsigned short*)alloc((size_t)256 * 256 * 2);
  unsigned short* dRb = (unsigned short*)alloc((size_t)256 * 256 * 2);
  unsigned short* Eb  = (unsigned short*)alloc((size_t)512 * 256 * 2);
  unsigned short* Gb  = (unsigned short*)alloc((size_t)1024 * 256 * 2);
  float* carry  = (float*)alloc((size_t)2 * NCHUNK * 512 * 4);
  float* prefix = (float*)alloc((size_t)2 * NCHUNK * 512 * 4);
  (void)ws_size; (void)in_sizes; (void)n_in; (void)out_size;

  // --- weight prep ---
  transpose_cast<<<dim3(32, 8), dim3(32, 8), 0, stream>>>(F, Ft, 256, 1024);
  transpose_cast<<<dim3(32, 8), dim3(32, 8), 0, stream>>>(Hp, Ht, 256, 1024);
  cast_flat<<<(65536 / 4 + 255) / 256, 256, 0, stream>>>(dP, dPb, 65536 / 4, 1.f);
  cast_flat<<<(65536 / 4 + 255) / 256, 256, 0, stream>>>(dR, dRb, 65536 / 4, 1.f);
  cast_flat<<<(131072 / 4 + 255) / 256, 256, 0, stream>>>(E, Eb, 131072 / 4, 1.f);
  cast_flat<<<(262144 / 4 + 255) / 256, 256, 0, stream>>>(G, Gb, 262144 / 4, 1.f);
  // u -> A2 cols [0,1024)
  cast_strided<<<((L_SEQ * 256) + 255) / 256, 256, 0, stream>>>(u, 1024, A2, 2048, L_SEQ, 1024, 1.f);
  // B_im -> W1 rows [512,1024)
  cast_flat<<<((512 * 1024 / 4) + 255) / 256, 256, 0, stream>>>(Bim, W1 + (size_t)512 * 1024, 512 * 1024 / 4, 1.f);
  // 2*C_re -> Wy cols [1024,1536); -2*C_im -> Wy cols [1536,2048)
  cast_strided<<<((1024 * 128) + 255) / 256, 256, 0, stream>>>(Cre, 512, Wy + 1024, 2048, 1024, 512, 2.f);
  cast_strided<<<((1024 * 128) + 255) / 256, 256, 0, stream>>>(Cim, 512, Wy + 1536, 2048, 1024, 512, -2.f);

  // FpT = Ft @ dP^T  (1024x256), HrT = Ht @ dR^T
  gemm_bt<0, 0, 1><<<dim3(8, 2), 256, 0, stream>>>(Ft, 256, dPb, 256, nullptr, 0, FpT, 256, nullptr, 0, 256);
  gemm_bt<0, 0, 1><<<dim3(8, 2), 256, 0, stream>>>(Ht, 256, dRb, 256, nullptr, 0, HrT, 256, nullptr, 0, 256);
  // W1 rows [0,512) = B_re + E @ FpT^T   (512x1024)
  gemm_bt<1, 0, 1><<<dim3(4, 8), 256, 0, stream>>>(Eb, 256, FpT, 256, nullptr, 0, W1, 1024, Bre, 1024, 256);
  // Wy cols [0,1024) = D + G @ HrT^T     (1024x1024)
  gemm_bt<1, 0, 1><<<dim3(8, 8), 256, 0, stream>>>(Gb, 256, HrT, 256, nullptr, 0, Wy, 2048, Dm, 1024, 256);

  // Bu = u @ W1^T   (8192x1024, K=1024)
  gemm_bt<0, 1, 0><<<dim3(64, 8), 256, 0, stream>>>(A2, 2048, W1, 1024, Bu, 1024, nullptr, 0, nullptr, 0, 1024);

  // scan
  scan_carry<<<128, 256, 0, stream>>>(Bu, lre, lim, carry);
  scan_prefix<<<1, 512, 0, stream>>>(carry, lre, lim, prefix);
  scan_apply<<<128, 256, 0, stream>>>(Bu, lre, lim, prefix, A2);

  // y = [u | x_re | x_im] @ Wy^T   (8192x1024, K=2048)
  gemm_bt<0, 1, 0><<<dim3(64, 8), 256, 0, stream>>>(A2, 2048, Wy, 2048, y, 1024, nullptr, 0, nullptr, 0, 2048);
}

// Round 2
// 270.606 us; speedup vs baseline: 1.0600x; 1.0600x over previous
//
#include <hip/hip_runtime.h>
#include <stdint.h>

#define L_SEQ 8192
#define NCHUNK 64
#define CHUNK  128

typedef __attribute__((ext_vector_type(8))) short bf16x8;
typedef __attribute__((ext_vector_type(4))) float f32x4;

__device__ inline unsigned short f2bf(float x) {
  unsigned u = __builtin_bit_cast(unsigned, x);
  unsigned r = (u + 0x7fffu + ((u >> 16) & 1u)) >> 16;
  return (unsigned short)r;
}

#define GLD16(g, l)                                                            \
  __builtin_amdgcn_global_load_lds(                                            \
      (const __attribute__((address_space(1))) unsigned int*)(g),              \
      (__attribute__((address_space(3))) unsigned int*)(l), 16, 0, 0)

// ---------------------------------------------------------------------------
// Fused weight-prep kernel. One dispatch replaces 9 cast/transpose launches.
// Work is indexed in 4-element quads; all job boundaries are multiples of 256
// threads so each block is job-uniform.
// ---------------------------------------------------------------------------
__global__ __launch_bounds__(256) void prep(
    const float* __restrict__ F, const float* __restrict__ Hp,
    const float* __restrict__ dP, const float* __restrict__ dR,
    const float* __restrict__ E, const float* __restrict__ G,
    const float* __restrict__ Bim, const float* __restrict__ Cre,
    const float* __restrict__ Cim, const float* __restrict__ u,
    unsigned short* __restrict__ Ft, unsigned short* __restrict__ Ht,
    unsigned short* __restrict__ dPb, unsigned short* __restrict__ dRb,
    unsigned short* __restrict__ Eb, unsigned short* __restrict__ Gb,
    unsigned short* __restrict__ W1im, unsigned short* __restrict__ Wy,
    unsigned short* __restrict__ A2) {
  int q = blockIdx.x * 256 + threadIdx.x;
  if (q < 65536) {  // Ft (1024x256) = F^T
    int e = q * 4, i = e >> 8, j = e & 255;
    ushort4 o;
    o.x = f2bf(F[(size_t)(j + 0) * 1024 + i]);
    o.y = f2bf(F[(size_t)(j + 1) * 1024 + i]);
    o.z = f2bf(F[(size_t)(j + 2) * 1024 + i]);
    o.w = f2bf(F[(size_t)(j + 3) * 1024 + i]);
    *(ushort4*)(Ft + e) = o;
  } else if (q < 131072) {  // Ht = Hp^T
    int e = (q - 65536) * 4, i = e >> 8, j = e & 255;
    ushort4 o;
    o.x = f2bf(Hp[(size_t)(j + 0) * 1024 + i]);
    o.y = f2bf(Hp[(size_t)(j + 1) * 1024 + i]);
    o.z = f2bf(Hp[(size_t)(j + 2) * 1024 + i]);
    o.w = f2bf(Hp[(size_t)(j + 3) * 1024 + i]);
    *(ushort4*)(Ht + e) = o;
  } else if (q < 147456) {  // dPb copy
    int e = (q - 131072) * 4;
    float4 v = *(const float4*)(dP + e);
    ushort4 o = {f2bf(v.x), f2bf(v.y), f2bf(v.z), f2bf(v.w)};
    *(ushort4*)(dPb + e) = o;
  } else if (q < 163840) {  // dRb copy
    int e = (q - 147456) * 4;
    float4 v = *(const float4*)(dR + e);
    ushort4 o = {f2bf(v.x), f2bf(v.y), f2bf(v.z), f2bf(v.w)};
    *(ushort4*)(dRb + e) = o;
  } else if (q < 196608) {  // Eb copy
    int e = (q - 163840) * 4;
    float4 v = *(const float4*)(E + e);
    ushort4 o = {f2bf(v.x), f2bf(v.y), f2bf(v.z), f2bf(v.w)};
    *(ushort4*)(Eb + e) = o;
  } else if (q < 262144) {  // Gb copy
    int e = (q - 196608) * 4;
    float4 v = *(const float4*)(G + e);
    ushort4 o = {f2bf(v.x), f2bf(v.y), f2bf(v.z), f2bf(v.w)};
    *(ushort4*)(Gb + e) = o;
  } else if (q < 393216) {  // B_im -> W1 rows [512,1024)
    int e = (q - 262144) * 4;
    float4 v = *(const float4*)(Bim + e);
    ushort4 o = {f2bf(v.x), f2bf(v.y), f2bf(v.z), f2bf(v.w)};
    *(ushort4*)(W1im + e) = o;
  } else if (q < 524288) {  // 2*C_re -> Wy cols [1024,1536)
    int e = (q - 393216) * 4, i = e >> 9, j = e & 511;
    float4 v = *(const float4*)(Cre + (size_t)i * 512 + j);
    ushort4 o = {f2bf(2.f * v.x), f2bf(2.f * v.y), f2bf(2.f * v.z), f2bf(2.f * v.w)};
    *(ushort4*)(Wy + (size_t)i * 2048 + 1024 + j) = o;
  } else if (q < 655360) {  // -2*C_im -> Wy cols [1536,2048)
    int e = (q - 524288) * 4, i = e >> 9, j = e & 511;
    float4 v = *(const float4*)(Cim + (size_t)i * 512 + j);
    ushort4 o = {f2bf(-2.f * v.x), f2bf(-2.f * v.y), f2bf(-2.f * v.z), f2bf(-2.f * v.w)};
    *(ushort4*)(Wy + (size_t)i * 2048 + 1536 + j) = o;
  } else {  // u -> A2 cols [0,1024)
    int e = (q - 655360) * 4, i = e >> 10, j = e & 1023;
    float4 v = *(const float4*)(u + (size_t)i * 1024 + j);
    ushort4 o = {f2bf(v.x), f2bf(v.y), f2bf(v.z), f2bf(v.w)};
    *(ushort4*)(A2 + (size_t)i * 2048 + j) = o;
  }
}

// ---------------------------------------------------------------------------
// bf16 MFMA GEMM body: C(MxN) = A(MxK) @ B(NxK)^T [+ Add]
// 128x128 tile, 4 waves (2x2), global_load_lds width-16 staging (m97 rung).
// ---------------------------------------------------------------------------
template <int HAS_ADD, int OUT_F32, int OUT_BF16>
__device__ __forceinline__ void gemm_body(
    const unsigned short* __restrict__ A, int lda,
    const unsigned short* __restrict__ B, int ldb,
    float* __restrict__ C, int ldc,
    unsigned short* __restrict__ Cb, int ldcb,
    const float* __restrict__ Add, int ldadd, int K, int m0, int n0,
    unsigned short* sA, unsigned short* sB) {
  const int tid = threadIdx.x;
  const int lane = tid & 63, wave = tid >> 6;
  const int wm = wave >> 1, wn = wave & 1;
  const int frow = lane & 15, fg = lane >> 4;

  // staging: wave w owns rows [w*32, w*32+32) of both tiles (two 16-row segs)
  const int srow = lane >> 2;          // 0..15
  const int scol = (lane & 3) * 8;     // shorts
  const unsigned short* gA0 = A + (size_t)(m0 + wave * 32 + srow) * lda + scol;
  const unsigned short* gA1 = gA0 + (size_t)16 * lda;
  const unsigned short* gB0 = B + (size_t)(n0 + wave * 32 + srow) * ldb + scol;
  const unsigned short* gB1 = gB0 + (size_t)16 * ldb;
  unsigned short* lA0 = sA + wave * 1024;
  unsigned short* lA1 = lA0 + 512;
  unsigned short* lB0 = sB + wave * 1024;
  unsigned short* lB1 = lB0 + 512;

  f32x4 acc[4][4] = {};

  for (int kt = 0; kt < K; kt += 32) {
    __syncthreads();  // prior ds_reads complete before LDS overwrite
    GLD16(gA0 + kt, lA0);
    GLD16(gA1 + kt, lA1);
    GLD16(gB0 + kt, lB0);
    GLD16(gB1 + kt, lB1);
    __syncthreads();  // compiler drains vmcnt(0) before this barrier
    bf16x8 fa[4], fb[4];
#pragma unroll
    for (int f = 0; f < 4; ++f) {
      fa[f] = *(const bf16x8*)(sA + (wm * 64 + f * 16 + frow) * 32 + fg * 8);
      fb[f] = *(const bf16x8*)(sB + (wn * 64 + f * 16 + frow) * 32 + fg * 8);
    }
#pragma unroll
    for (int i = 0; i < 4; ++i)
#pragma unroll
      for (int j = 0; j < 4; ++j)
        acc[i][j] = __builtin_amdgcn_mfma_f32_16x16x32_bf16(fa[i], fb[j], acc[i][j], 0, 0, 0);
  }

  const int crow4 = (lane >> 4) * 4, ccol = lane & 15;
#pragma unroll
  for (int i = 0; i < 4; ++i)
#pragma unroll
    for (int j = 0; j < 4; ++j)
#pragma unroll
      for (int q = 0; q < 4; ++q) {
        int r = m0 + wm * 64 + i * 16 + crow4 + q;
        int c = n0 + wn * 64 + j * 16 + ccol;
        float v = acc[i][j][q];
        if (HAS_ADD) v += Add[(size_t)r * ldadd + c];
        if (OUT_F32) C[(size_t)r * ldc + c] = v;
        if (OUT_BF16) Cb[(size_t)r * ldcb + c] = f2bf(v);
      }
}

template <int HAS_ADD, int OUT_F32, int OUT_BF16>
__global__ __launch_bounds__(256) void gemm_bt(
    const unsigned short* __restrict__ A, int lda,
    const unsigned short* __restrict__ B, int ldb,
    float* __restrict__ C, int ldc,
    unsigned short* __restrict__ Cb, int ldcb,
    const float* __restrict__ Add, int ldadd, int K) {
  __shared__ __align__(16) unsigned short sA[128 * 32];
  __shared__ __align__(16) unsigned short sB[128 * 32];
  gemm_body<HAS_ADD, OUT_F32, OUT_BF16>(A, lda, B, ldb, C, ldc, Cb, ldcb, Add,
                                        ldadd, K, blockIdx.x * 128,
                                        blockIdx.y * 128, sA, sB);
}

struct GemmP {
  const unsigned short* A; int lda;
  const unsigned short* B; int ldb;
  float* C; int ldc;
  unsigned short* Cb; int ldcb;
  const float* Add; int ldadd;
  int K; int gx;
};

template <int HAS_ADD, int OUT_F32, int OUT_BF16>
__global__ __launch_bounds__(256) void gemm_bt_dual(GemmP p0, GemmP p1) {
  __shared__ __align__(16) unsigned short sA[128 * 32];
  __shared__ __align__(16) unsigned short sB[128 * 32];
  GemmP p = blockIdx.z ? p1 : p0;
  if ((int)blockIdx.x >= p.gx) return;
  gemm_body<HAS_ADD, OUT_F32, OUT_BF16>(p.A, p.lda, p.B, p.ldb, p.C, p.ldc,
                                        p.Cb, p.ldcb, p.Add, p.ldadd, p.K,
                                        blockIdx.x * 128, blockIdx.y * 128, sA, sB);
}

// ---------------------------------------------------------------------------
// Scan phase 1: per (channel, chunk) local scan from 0; carry -> [p][c] float2
// ---------------------------------------------------------------------------
__global__ __launch_bounds__(256) void scan_carry(const float* __restrict__ Bu,
                                                  const float* __restrict__ lre,
                                                  const float* __restrict__ lim,
                                                  float2* __restrict__ carry2) {
  int g = blockIdx.x * 256 + threadIdx.x;  // 0..32767
  int p = g & 511, c = g >> 9;
  float ar = lre[p], ai = lim[p];
  float sr = 0.f, si = 0.f;
  const float* base = Bu + (size_t)c * CHUNK * 1024 + p;
#pragma unroll 4
  for (int i = 0; i < CHUNK; ++i) {
    float br = base[(size_t)i * 1024];
    float bi = base[(size_t)i * 1024 + 512];
    float nr = ar * sr - ai * si + br;
    float ni = ar * si + ai * sr + bi;
    sr = nr; si = ni;
  }
  carry2[(size_t)p * NCHUNK + c] = make_float2(sr, si);
}

// ---------------------------------------------------------------------------
// Scan phase 2: combine chunk carries per channel; 16-deep load batches.
// ---------------------------------------------------------------------------
__global__ __launch_bounds__(512) void scan_prefix(const float2* __restrict__ carry2,
                                                   const float* __restrict__ lre,
                                                   const float* __restrict__ lim,
                                                   float2* __restrict__ prefix2) {
  int p = threadIdx.x;  // 512
  float ar = lre[p], ai = lim[p];
  float cr = ar, ci = ai;  // lam^128 via 7 squarings
#pragma unroll
  for (int s = 0; s < 7; ++s) {
    float t = cr * cr - ci * ci;
    ci = 2.f * cr * ci;
    cr = t;
  }
  float sr = 0.f, si = 0.f;
  const float2* cp = carry2 + (size_t)p * NCHUNK;
  float2* pp = prefix2 + (size_t)p * NCHUNK;
  for (int cb = 0; cb < NCHUNK; cb += 16) {
    float2 cv[16];
#pragma unroll
    for (int i = 0; i < 16; ++i) cv[i] = cp[cb + i];
#pragma unroll
    for (int i = 0; i < 16; ++i) {
      float nr = cr * sr - ci * si + cv[i].x;
      float ni = cr * si + ci * sr + cv[i].y;
      sr = nr; si = ni;
      pp[cb + i] = make_float2(sr, si);
    }
  }
}

// ---------------------------------------------------------------------------
// Scan phase 3: re-scan with carry-in, write bf16 x into A2 cols [1024,2048)
// ---------------------------------------------------------------------------
__global__ __launch_bounds__(256) void scan_apply(const float* __restrict__ Bu,
                                                  const float* __restrict__ lre,
                                                  const float* __restrict__ lim,
                                                  const float2* __restrict__ prefix2,
                                                  unsigned short* __restrict__ A2) {
  int g = blockIdx.x * 256 + threadIdx.x;
  int p = g & 511, c = g >> 9;
  float ar = lre[p], ai = lim[p];
  float sr = 0.f, si = 0.f;
  if (c > 0) {
    float2 pr = prefix2[(size_t)p * NCHUNK + c - 1];
    sr = pr.x; si = pr.y;
  }
  const float* base = Bu + (size_t)c * CHUNK * 1024 + p;
  unsigned short* ob = A2 + (size_t)c * CHUNK * 2048 + 1024 + p;
#pragma unroll 4
  for (int i = 0; i < CHUNK; ++i) {
    float br = base[(size_t)i * 1024];
    float bi = base[(size_t)i * 1024 + 512];
    float nr = ar * sr - ai * si + br;
    float ni = ar * si + ai * sr + bi;
    sr = nr; si = ni;
    ob[(size_t)i * 2048] = f2bf(sr);
    ob[(size_t)i * 2048 + 512] = f2bf(si);
  }
}

// ---------------------------------------------------------------------------
extern "C" void kernel_launch(void* const* d_in, const int* in_sizes, int n_in,
                              void* d_out, int out_size, void* d_ws, size_t ws_size,
                              hipStream_t stream) {
  const float* u   = (const float*)d_in[0];
  const float* F   = (const float*)d_in[1];
  const float* Hp  = (const float*)d_in[2];
  const float* dP  = (const float*)d_in[3];
  const float* dR  = (const float*)d_in[4];
  const float* E   = (const float*)d_in[5];
  const float* G   = (const float*)d_in[6];
  const float* lre = (const float*)d_in[7];
  const float* lim = (const float*)d_in[8];
  const float* Bre = (const float*)d_in[9];
  const float* Bim = (const float*)d_in[10];
  const float* Cre = (const float*)d_in[11];
  const float* Cim = (const float*)d_in[12];
  const float* Dm  = (const float*)d_in[13];
  float* y = (float*)d_out;

  uint8_t* ws = (uint8_t*)d_ws;
  size_t off = 0;
  auto alloc = [&](size_t bytes) {
    void* p = ws + off;
    off += (bytes + 255) & ~(size_t)255;
    return p;
  };
  unsigned short* A2  = (unsigned short*)alloc((size_t)L_SEQ * 2048 * 2);
  unsigned short* W1  = (unsigned short*)alloc((size_t)1024 * 1024 * 2);
  unsigned short* Wy  = (unsigned short*)alloc((size_t)1024 * 2048 * 2);
  float*          Bu  = (float*)alloc((size_t)L_SEQ * 1024 * 4);
  unsigned short* Ft  = (unsigned short*)alloc((size_t)1024 * 256 * 2);
  unsigned short* Ht  = (unsigned short*)alloc((size_t)1024 * 256 * 2);
  unsigned short* FpT = (unsigned short*)alloc((size_t)1024 * 256 * 2);
  unsigned short* HrT = (unsigned short*)alloc((size_t)1024 * 256 * 2);
  unsigned short* dPb = (unsigned short*)alloc((size_t)256 * 256 * 2);
  unsigned short* dRb = (unsigned short*)alloc((size_t)256 * 256 * 2);
  unsigned short* Eb  = (unsigned short*)alloc((size_t)512 * 256 * 2);
  unsigned short* Gb  = (unsigned short*)alloc((size_t)1024 * 256 * 2);
  float* carry  = (float*)alloc((size_t)512 * NCHUNK * 8);
  float* prefix = (float*)alloc((size_t)512 * NCHUNK * 8);
  (void)ws_size; (void)in_sizes; (void)n_in; (void)out_size;

  // 1) fused prep (9 former launches)
  prep<<<10752, 256, 0, stream>>>(F, Hp, dP, dR, E, G, Bim, Cre, Cim, u,
                                  Ft, Ht, dPb, dRb, Eb, Gb,
                                  W1 + (size_t)512 * 1024, Wy, A2);

  // 2) FpT = Ft@dP^T, HrT = Ht@dR^T (paired)
  GemmP pa = {Ft, 256, dPb, 256, nullptr, 0, FpT, 256, nullptr, 0, 256, 8};
  GemmP pb = {Ht, 256, dRb, 256, nullptr, 0, HrT, 256, nullptr, 0, 256, 8};
  gemm_bt_dual<0, 0, 1><<<dim3(8, 2, 2), 256, 0, stream>>>(pa, pb);

  // 3) W1[0:512) = Bre + E@FpT^T ; Wy[:, 0:1024) = D + G@HrT^T (paired)
  GemmP pc = {Eb, 256, FpT, 256, nullptr, 0, W1, 1024, Bre, 1024, 256, 4};
  GemmP pd = {Gb, 256, HrT, 256, nullptr, 0, Wy, 2048, Dm, 1024, 256, 8};
  gemm_bt_dual<1, 0, 1><<<dim3(8, 8, 2), 256, 0, stream>>>(pc, pd);

  // 4) Bu = u @ W1^T (8192x1024, K=1024)
  gemm_bt<0, 1, 0><<<dim3(64, 8), 256, 0, stream>>>(A2, 2048, W1, 1024, Bu, 1024,
                                                    nullptr, 0, nullptr, 0, 1024);

  // 5) scan
  scan_carry<<<128, 256, 0, stream>>>(Bu, lre, lim, (float2*)carry);
  scan_prefix<<<1, 512, 0, stream>>>((const float2*)carry, lre, lim, (float2*)prefix);
  scan_apply<<<128, 256, 0, stream>>>(Bu, lre, lim, (const float2*)prefix, A2);

  // 6) y = [u | x_re | x_im] @ Wy^T (8192x1024, K=2048)
  gemm_bt<0, 1, 0><<<dim3(64, 8), 256, 0, stream>>>(A2, 2048, Wy, 2048, y, 1024,
                                                    nullptr, 0, nullptr, 0, 2048);
}

// Round 4
// 240.982 us; speedup vs baseline: 1.1904x; 1.1229x over previous
//
#include <hip/hip_runtime.h>
#include <stdint.h>

#define L_SEQ 8192
#define NCHUNK 64
#define CHUNK  128

typedef __attribute__((ext_vector_type(8))) short bf16x8;
typedef __attribute__((ext_vector_type(4))) float f32x4;

__device__ inline unsigned short f2bf(float x) {
  unsigned u = __builtin_bit_cast(unsigned, x);
  unsigned r = (u + 0x7fffu + ((u >> 16) & 1u)) >> 16;
  return (unsigned short)r;
}
__device__ inline float bf2f(unsigned short b) {
  unsigned u = ((unsigned)b) << 16;
  return __builtin_bit_cast(float, u);
}

#define GLD16(g, l)                                                            \
  __builtin_amdgcn_global_load_lds(                                            \
      (const __attribute__((address_space(1))) unsigned int*)(g),              \
      (__attribute__((address_space(3))) unsigned int*)(l), 16, 0, 0)

// ---------------------------------------------------------------------------
// Fused prep: LDS-tiled transposes for F/Hp + flat casts + interleaved packs.
// Block-range dispatch (all branches block-uniform).
//   [0,256)    Ft = F^T            (1024x256 bf16)
//   [256,512)  Ht = Hp^T
//   [512,576)  dPb                  (256x256)
//   [576,640)  dRb
//   [640,768)  Eb                   (512x256)
//   [768,1024) Gb                   (1024x256)
//   [1024,1536) Bim -> W1 odd rows  (row 2p+1)
//   [1536,2560) Cre/Cim -> Wy cols [1024,2048) interleaved (2Re, -2Im)
//   [2560,10752) u -> A2 cols [0,1024)
// ---------------------------------------------------------------------------
__global__ __launch_bounds__(256) void prep(
    const float* __restrict__ F, const float* __restrict__ Hp,
    const float* __restrict__ dP, const float* __restrict__ dR,
    const float* __restrict__ E, const float* __restrict__ G,
    const float* __restrict__ Bim, const float* __restrict__ Cre,
    const float* __restrict__ Cim, const float* __restrict__ u,
    unsigned short* __restrict__ Ft, unsigned short* __restrict__ Ht,
    unsigned short* __restrict__ dPb, unsigned short* __restrict__ dRb,
    unsigned short* __restrict__ Eb, unsigned short* __restrict__ Gb,
    unsigned short* __restrict__ W1, unsigned short* __restrict__ Wy,
    unsigned short* __restrict__ A2) {
  __shared__ float tile[32][33];
  const int b = blockIdx.x, tid = threadIdx.x;
  if (b < 512) {  // transpose F (b<256) or Hp (b>=256)
    const float* src = (b < 256) ? F : Hp;
    unsigned short* dst = (b < 256) ? Ft : Ht;
    int bb = b & 255;
    int bx = bb & 31, by = bb >> 5;  // bx over 1024 cols, by over 256 rows
    int tx = tid & 31, ty = tid >> 5;
#pragma unroll
    for (int dy = 0; dy < 32; dy += 8)
      tile[ty + dy][tx] = src[(size_t)(by * 32 + ty + dy) * 1024 + bx * 32 + tx];
    __syncthreads();
#pragma unroll
    for (int dy = 0; dy < 32; dy += 8)
      dst[(size_t)(bx * 32 + ty + dy) * 256 + by * 32 + tx] = f2bf(tile[tx][ty + dy]);
    return;
  }
  if (b < 1024) {  // flat casts
    const float* src;
    unsigned short* dst;
    int q;
    if (b < 576)      { src = dP; dst = dPb; q = (b - 512) * 256 + tid; }
    else if (b < 640) { src = dR; dst = dRb; q = (b - 576) * 256 + tid; }
    else if (b < 768) { src = E;  dst = Eb;  q = (b - 640) * 256 + tid; }
    else              { src = G;  dst = Gb;  q = (b - 768) * 256 + tid; }
    int e = q * 4;
    float4 v = *(const float4*)(src + e);
    ushort4 o = {f2bf(v.x), f2bf(v.y), f2bf(v.z), f2bf(v.w)};
    *(ushort4*)(dst + e) = o;
    return;
  }
  if (b < 1536) {  // Bim row p -> W1 row 2p+1
    int q = (b - 1024) * 256 + tid;
    int e = q * 4, p = e >> 10, j = e & 1023;
    float4 v = *(const float4*)(Bim + (size_t)p * 1024 + j);
    ushort4 o = {f2bf(v.x), f2bf(v.y), f2bf(v.z), f2bf(v.w)};
    *(ushort4*)(W1 + (size_t)(2 * p + 1) * 1024 + j) = o;
    return;
  }
  if (b < 2560) {  // Cre/Cim -> Wy interleaved: col 1024+2p=2Re, 1025+2p=-2Im
    int q = (b - 1536) * 256 + tid;   // 262144 threads: i=row, jp=pair
    int i = q >> 8, jp = (q & 255) * 2;
    float2 re = *(const float2*)(Cre + (size_t)i * 512 + jp);
    float2 im = *(const float2*)(Cim + (size_t)i * 512 + jp);
    ushort4 o = {f2bf(2.f * re.x), f2bf(-2.f * im.x), f2bf(2.f * re.y), f2bf(-2.f * im.y)};
    *(ushort4*)(Wy + (size_t)i * 2048 + 1024 + 2 * jp) = o;
    return;
  }
  {  // u -> A2 cols [0,1024)
    int q = (b - 2560) * 256 + tid;
    int e = q * 4, i = e >> 10, j = e & 1023;
    float4 v = *(const float4*)(u + (size_t)i * 1024 + j);
    ushort4 o = {f2bf(v.x), f2bf(v.y), f2bf(v.z), f2bf(v.w)};
    *(ushort4*)(A2 + (size_t)i * 2048 + j) = o;
  }
}

// ---------------------------------------------------------------------------
// bf16 MFMA GEMM body: C(MxN) = A(MxK) @ B(NxK)^T [+ Add]
// 128x128 tile, 4 waves (2x2), global_load_lds staging, DOUBLE-BUFFERED
// 2-phase: stage(t+1) issued before compute(t); ONE barrier per K-step.
// ---------------------------------------------------------------------------
template <int HAS_ADD, int OUT_F32, int OUT_BF16>
__device__ __forceinline__ void gemm_body(
    const unsigned short* __restrict__ A, int lda,
    const unsigned short* __restrict__ B, int ldb,
    float* __restrict__ C, int ldc,
    unsigned short* __restrict__ Cb, int ldcb,
    const float* __restrict__ Add, int ldadd, int K, int m0, int n0,
    unsigned short* sA, unsigned short* sB) {
  const int tid = threadIdx.x;
  const int lane = tid & 63, wave = tid >> 6;
  const int wm = wave >> 1, wn = wave & 1;
  const int frow = lane & 15, fg = lane >> 4;

  // staging: wave w owns rows [w*32, w*32+32) of both tiles (two 16-row segs)
  const int srow = lane >> 2;
  const int scol = (lane & 3) * 8;
  const unsigned short* gA0 = A + (size_t)(m0 + wave * 32 + srow) * lda + scol;
  const unsigned short* gA1 = gA0 + (size_t)16 * lda;
  const unsigned short* gB0 = B + (size_t)(n0 + wave * 32 + srow) * ldb + scol;
  const unsigned short* gB1 = gB0 + (size_t)16 * ldb;

  f32x4 acc[4][4] = {};
  const int nt = K >> 5;

  // prologue: stage tile 0 into buffer 0
  {
    unsigned short* a0 = sA + wave * 1024;
    unsigned short* b0 = sB + wave * 1024;
    GLD16(gA0, a0); GLD16(gA1, a0 + 512);
    GLD16(gB0, b0); GLD16(gB1, b0 + 512);
  }
  __syncthreads();

  for (int t = 0; t < nt; ++t) {
    const int cur = (t & 1) * 4096;
    if (t + 1 < nt) {  // stage next tile into other buffer
      const int nxt = 4096 - cur;
      const int kt = (t + 1) * 32;
      unsigned short* a0 = sA + nxt + wave * 1024;
      unsigned short* b0 = sB + nxt + wave * 1024;
      GLD16(gA0 + kt, a0); GLD16(gA1 + kt, a0 + 512);
      GLD16(gB0 + kt, b0); GLD16(gB1 + kt, b0 + 512);
    }
    const unsigned short* bA = sA + cur;
    const unsigned short* bB = sB + cur;
    bf16x8 fa[4], fb[4];
#pragma unroll
    for (int f = 0; f < 4; ++f) {
      fa[f] = *(const bf16x8*)(bA + (wm * 64 + f * 16 + frow) * 32 + fg * 8);
      fb[f] = *(const bf16x8*)(bB + (wn * 64 + f * 16 + frow) * 32 + fg * 8);
    }
#pragma unroll
    for (int i = 0; i < 4; ++i)
#pragma unroll
      for (int j = 0; j < 4; ++j)
        acc[i][j] = __builtin_amdgcn_mfma_f32_16x16x32_bf16(fa[i], fb[j], acc[i][j], 0, 0, 0);
    __syncthreads();  // drains vmcnt (stage t+1 done) + all reads of cur done
  }

  const int crow4 = (lane >> 4) * 4, ccol = lane & 15;
#pragma unroll
  for (int i = 0; i < 4; ++i)
#pragma unroll
    for (int j = 0; j < 4; ++j)
#pragma unroll
      for (int q = 0; q < 4; ++q) {
        int r = m0 + wm * 64 + i * 16 + crow4 + q;
        int c = n0 + wn * 64 + j * 16 + ccol;
        float v = acc[i][j][q];
        if (HAS_ADD) v += Add[(size_t)r * ldadd + c];
        if (OUT_F32) C[(size_t)r * ldc + c] = v;
        if (OUT_BF16) Cb[(size_t)r * ldcb + c] = f2bf(v);
      }
}

template <int HAS_ADD, int OUT_F32, int OUT_BF16>
__global__ __launch_bounds__(256) void gemm_bt(
    const unsigned short* __restrict__ A, int lda,
    const unsigned short* __restrict__ B, int ldb,
    float* __restrict__ C, int ldc,
    unsigned short* __restrict__ Cb, int ldcb,
    const float* __restrict__ Add, int ldadd, int K) {
  __shared__ __align__(16) unsigned short sA[2 * 128 * 32];
  __shared__ __align__(16) unsigned short sB[2 * 128 * 32];
  gemm_body<HAS_ADD, OUT_F32, OUT_BF16>(A, lda, B, ldb, C, ldc, Cb, ldcb, Add,
                                        ldadd, K, blockIdx.x * 128,
                                        blockIdx.y * 128, sA, sB);
}

struct GemmP {
  const unsigned short* A; int lda;
  const unsigned short* B; int ldb;
  float* C; int ldc;
  unsigned short* Cb; int ldcb;
  const float* Add; int ldadd;
  int K; int gx;
};

template <int HAS_ADD, int OUT_F32, int OUT_BF16>
__global__ __launch_bounds__(256) void gemm_bt_dual(GemmP p0, GemmP p1) {
  __shared__ __align__(16) unsigned short sA[2 * 128 * 32];
  __shared__ __align__(16) unsigned short sB[2 * 128 * 32];
  GemmP p = blockIdx.z ? p1 : p0;
  if ((int)blockIdx.x >= p.gx) return;
  gemm_body<HAS_ADD, OUT_F32, OUT_BF16>(p.A, p.lda, p.B, p.ldb, p.C, p.ldc,
                                        p.Cb, p.ldcb, p.Add, p.ldadd, p.K,
                                        blockIdx.x * 128, blockIdx.y * 128, sA, sB);
}

// ---------------------------------------------------------------------------
// Scan over interleaved bf16 Bu: row i, col 2p = re, 2p+1 = im.
// ---------------------------------------------------------------------------
__global__ __launch_bounds__(256) void scan_carry(const unsigned short* __restrict__ Bub,
                                                  const float* __restrict__ lre,
                                                  const float* __restrict__ lim,
                                                  float2* __restrict__ carry2) {
  int g = blockIdx.x * 256 + threadIdx.x;  // 0..32767
  int p = g & 511, c = g >> 9;
  float ar = lre[p], ai = lim[p];
  float sr = 0.f, si = 0.f;
  const unsigned short* base = Bub + (size_t)c * CHUNK * 1024 + 2 * p;
#pragma unroll 8
  for (int i = 0; i < CHUNK; ++i) {
    unsigned w = *(const unsigned*)(base + (size_t)i * 1024);
    float br = bf2f((unsigned short)(w & 0xffff));
    float bi = bf2f((unsigned short)(w >> 16));
    float nr = ar * sr - ai * si + br;
    float ni = ar * si + ai * sr + bi;
    sr = nr; si = ni;
  }
  carry2[(size_t)p * NCHUNK + c] = make_float2(sr, si);
}

__global__ __launch_bounds__(512) void scan_prefix(const float2* __restrict__ carry2,
                                                   const float* __restrict__ lre,
                                                   const float* __restrict__ lim,
                                                   float2* __restrict__ prefix2) {
  int p = threadIdx.x;  // 512
  float ar = lre[p], ai = lim[p];
  float cr = ar, ci = ai;  // lam^128 via 7 squarings
#pragma unroll
  for (int s = 0; s < 7; ++s) {
    float t = cr * cr - ci * ci;
    ci = 2.f * cr * ci;
    cr = t;
  }
  float sr = 0.f, si = 0.f;
  const float2* cp = carry2 + (size_t)p * NCHUNK;
  float2* pp = prefix2 + (size_t)p * NCHUNK;
  for (int cb = 0; cb < NCHUNK; cb += 16) {
    float2 cv[16];
#pragma unroll
    for (int i = 0; i < 16; ++i) cv[i] = cp[cb + i];
#pragma unroll
    for (int i = 0; i < 16; ++i) {
      float nr = cr * sr - ci * si + cv[i].x;
      float ni = cr * si + ci * sr + cv[i].y;
      sr = nr; si = ni;
      pp[cb + i] = make_float2(sr, si);
    }
  }
}

// Re-scan with carry-in; write packed (re,im) bf16 into A2 cols [1024,2048).
__global__ __launch_bounds__(256) void scan_apply(const unsigned short* __restrict__ Bub,
                                                  const float* __restrict__ lre,
                                                  const float* __restrict__ lim,
                                                  const float2* __restrict__ prefix2,
                                                  unsigned short* __restrict__ A2) {
  int g = blockIdx.x * 256 + threadIdx.x;
  int p = g & 511, c = g >> 9;
  float ar = lre[p], ai = lim[p];
  float sr = 0.f, si = 0.f;
  if (c > 0) {
    float2 pr = prefix2[(size_t)p * NCHUNK + c - 1];
    sr = pr.x; si = pr.y;
  }
  const unsigned short* base = Bub + (size_t)c * CHUNK * 1024 + 2 * p;
  unsigned* ob = (unsigned*)(A2 + (size_t)c * CHUNK * 2048 + 1024 + 2 * p);
#pragma unroll 8
  for (int i = 0; i < CHUNK; ++i) {
    unsigned w = *(const unsigned*)(base + (size_t)i * 1024);
    float br = bf2f((unsigned short)(w & 0xffff));
    float bi = bf2f((unsigned short)(w >> 16));
    float nr = ar * sr - ai * si + br;
    float ni = ar * si + ai * sr + bi;
    sr = nr; si = ni;
    ob[(size_t)i * 1024] = (unsigned)f2bf(sr) | ((unsigned)f2bf(si) << 16);
  }
}

// ---------------------------------------------------------------------------
extern "C" void kernel_launch(void* const* d_in, const int* in_sizes, int n_in,
                              void* d_out, int out_size, void* d_ws, size_t ws_size,
                              hipStream_t stream) {
  const float* u   = (const float*)d_in[0];
  const float* F   = (const float*)d_in[1];
  const float* Hp  = (const float*)d_in[2];
  const float* dP  = (const float*)d_in[3];
  const float* dR  = (const float*)d_in[4];
  const float* E   = (const float*)d_in[5];
  const float* G   = (const float*)d_in[6];
  const float* lre = (const float*)d_in[7];
  const float* lim = (const float*)d_in[8];
  const float* Bre = (const float*)d_in[9];
  const float* Bim = (const float*)d_in[10];
  const float* Cre = (const float*)d_in[11];
  const float* Cim = (const float*)d_in[12];
  const float* Dm  = (const float*)d_in[13];
  float* y = (float*)d_out;

  uint8_t* ws = (uint8_t*)d_ws;
  size_t off = 0;
  auto alloc = [&](size_t bytes) {
    void* p = ws + off;
    off += (bytes + 255) & ~(size_t)255;
    return p;
  };
  unsigned short* A2  = (unsigned short*)alloc((size_t)L_SEQ * 2048 * 2);  // [u | x interleaved]
  unsigned short* W1  = (unsigned short*)alloc((size_t)1024 * 1024 * 2);   // rows 2p=B're, 2p+1=B'im
  unsigned short* Wy  = (unsigned short*)alloc((size_t)1024 * 2048 * 2);   // [D' | interleaved 2Cre/-2Cim]
  unsigned short* Bub = (unsigned short*)alloc((size_t)L_SEQ * 1024 * 2);  // bf16 interleaved
  unsigned short* Ft  = (unsigned short*)alloc((size_t)1024 * 256 * 2);
  unsigned short* Ht  = (unsigned short*)alloc((size_t)1024 * 256 * 2);
  unsigned short* FpT = (unsigned short*)alloc((size_t)1024 * 256 * 2);
  unsigned short* HrT = (unsigned short*)alloc((size_t)1024 * 256 * 2);
  unsigned short* dPb = (unsigned short*)alloc((size_t)256 * 256 * 2);
  unsigned short* dRb = (unsigned short*)alloc((size_t)256 * 256 * 2);
  unsigned short* Eb  = (unsigned short*)alloc((size_t)512 * 256 * 2);
  unsigned short* Gb  = (unsigned short*)alloc((size_t)1024 * 256 * 2);
  float* carry  = (float*)alloc((size_t)512 * NCHUNK * 8);
  float* prefix = (float*)alloc((size_t)512 * NCHUNK * 8);
  (void)ws_size; (void)in_sizes; (void)n_in; (void)out_size;

  // 1) fused prep
  prep<<<10752, 256, 0, stream>>>(F, Hp, dP, dR, E, G, Bim, Cre, Cim, u,
                                  Ft, Ht, dPb, dRb, Eb, Gb, W1, Wy, A2);

  // 2) FpT = Ft@dP^T, HrT = Ht@dR^T (paired)
  GemmP pa = {Ft, 256, dPb, 256, nullptr, 0, FpT, 256, nullptr, 0, 256, 8};
  GemmP pb = {Ht, 256, dRb, 256, nullptr, 0, HrT, 256, nullptr, 0, 256, 8};
  gemm_bt_dual<0, 0, 1><<<dim3(8, 2, 2), 256, 0, stream>>>(pa, pb);

  // 3) W1 even rows = Bre + E@FpT^T (ldcb=2048 -> row 2p); Wy[:,0:1024) = D + G@HrT^T
  GemmP pc = {Eb, 256, FpT, 256, nullptr, 0, W1, 2048, Bre, 1024, 256, 4};
  GemmP pd = {Gb, 256, HrT, 256, nullptr, 0, Wy, 2048, Dm, 1024, 256, 8};
  gemm_bt_dual<1, 0, 1><<<dim3(8, 8, 2), 256, 0, stream>>>(pc, pd);

  // 4) Bu (bf16, interleaved) = u @ W1^T
  gemm_bt<0, 0, 1><<<dim3(64, 8), 256, 0, stream>>>(A2, 2048, W1, 1024, nullptr, 0,
                                                    Bub, 1024, nullptr, 0, 1024);

  // 5) scan
  scan_carry<<<128, 256, 0, stream>>>(Bub, lre, lim, (float2*)carry);
  scan_prefix<<<1, 512, 0, stream>>>((const float2*)carry, lre, lim, (float2*)prefix);
  scan_apply<<<128, 256, 0, stream>>>(Bub, lre, lim, (const float2*)prefix, A2);

  // 6) y = [u | x] @ Wy^T
  gemm_bt<0, 1, 0><<<dim3(64, 8), 256, 0, stream>>>(A2, 2048, Wy, 2048, y, 1024,
                                                    nullptr, 0, nullptr, 0, 2048);
}